// Round 7
// baseline (418.601 us; speedup 1.0000x reference)
//
#include <hip/hip_runtime.h>
#include <math.h>

typedef unsigned short u16;
typedef unsigned int   u32;
using f32x4  = __attribute__((ext_vector_type(4))) float;
using bf16x8 = __attribute__((ext_vector_type(8))) __bf16;

#define HIDDEN   2880
#define QKVD     5120
#define QD       4096
#define TTOK     2048
#define NKV      8
#define QMULT    8
#define HD       64
#define NPAD     2944   // w_out rows padded to 23*128

// prep grid partition
#define PREP_QKV_BLOCKS  14400   // QKVD*HIDDEN/4/256
#define PREP_WOUT_BLOCKS 11776   // NPAD*QD/4/256
#define PREP_RMS_BLOCKS  2048

static __device__ __forceinline__ float bflo(u32 u){ return __uint_as_float(u << 16); }
static __device__ __forceinline__ float bfhi(u32 u){ return __uint_as_float(u & 0xffff0000u); }
static __device__ __forceinline__ u16 f2bf(float f){
    u32 u = __float_as_uint(f);
    u32 r = (u + 0x7fffu + ((u >> 16) & 1u)) >> 16;
    return (u16)r;
}

static __device__ __forceinline__ void glds16(const void* g, void* l) {
    __builtin_amdgcn_global_load_lds(
        (__attribute__((address_space(1))) void*)g,
        (__attribute__((address_space(3))) void*)l,
        16, 0, 0);
}

// ---------------- fused prep: w_qkv cvt | w_out cvt+pad | rmsnorm ----------------
__global__ __launch_bounds__(256) void prep_kernel(const float* __restrict__ w_qkv,
                                                   u16* __restrict__ wqkv_bf,
                                                   const float* __restrict__ w_out,
                                                   u16* __restrict__ wout_bf,
                                                   const float* __restrict__ x,
                                                   const float* __restrict__ scale,
                                                   u16* __restrict__ h) {
    const int b = blockIdx.x;
    const int tid = threadIdx.x;
    if (b < PREP_QKV_BLOCKS) {
        int i = b * 256 + tid;
        float4 f = ((const float4*)w_qkv)[i];
        ushort4 o;
        o.x = f2bf(f.x); o.y = f2bf(f.y); o.z = f2bf(f.z); o.w = f2bf(f.w);
        ((ushort4*)wqkv_bf)[i] = o;
    } else if (b < PREP_QKV_BLOCKS + PREP_WOUT_BLOCKS) {
        int i = (b - PREP_QKV_BLOCKS) * 256 + tid;
        int idx = i * 4;
        int row = idx >> 12;        // /4096
        int col = idx & 4095;
        ushort4 o;
        if (row < HIDDEN) {
            float4 f = *(const float4*)(w_out + (long)row * QD + col);
            o.x = f2bf(f.x); o.y = f2bf(f.y); o.z = f2bf(f.z); o.w = f2bf(f.w);
        } else {
            o.x = 0; o.y = 0; o.z = 0; o.w = 0;
        }
        ((ushort4*)wout_bf)[i] = o;
    } else {
        const int t = b - (PREP_QKV_BLOCKS + PREP_WOUT_BLOCKS);
        const float4* xr = (const float4*)(x + (long)t * HIDDEN);
        float4 v[3];
        float ss = 0.f;
        #pragma unroll
        for (int it = 0; it < 3; ++it) {
            int i4 = tid + it * 256;
            if (i4 < 720) {
                v[it] = xr[i4];
                ss += v[it].x*v[it].x + v[it].y*v[it].y + v[it].z*v[it].z + v[it].w*v[it].w;
            }
        }
        #pragma unroll
        for (int off = 32; off > 0; off >>= 1) ss += __shfl_down(ss, off);
        __shared__ float red[4];
        if ((tid & 63) == 0) red[tid >> 6] = ss;
        __syncthreads();
        float tot = red[0] + red[1] + red[2] + red[3];
        float rr = rsqrtf(tot * (1.0f / HIDDEN) + 1e-5f);
        ushort4* hr = (ushort4*)(h + (long)t * HIDDEN);
        #pragma unroll
        for (int it = 0; it < 3; ++it) {
            int i4 = tid + it * 256;
            if (i4 < 720) {
                float4 s4 = ((const float4*)scale)[i4];
                ushort4 o;
                o.x = f2bf(v[it].x * rr * s4.x);
                o.y = f2bf(v[it].y * rr * s4.y);
                o.z = f2bf(v[it].z * rr * s4.z);
                o.w = f2bf(v[it].w * rr * s4.w);
                hr[i4] = o;
            }
        }
    }
}

// ---------------- split-K partial GEMM: Cz[M,N] = A[M,K(kb:ke)] @ B[N,K]^T ----------
// 128x128 tile, BK=32 dbuf prefetch, split-K via blockIdx.z (residency without
// shrinking the tile — R5 lesson). LDS layout is k-chunk-major per 16-row
// panel: staging lane (row=lane&15, chunk=lane>>4) makes BOTH the glds write
// AND every MFMA frag ds_read_b128 land at panel_base + lane*16 — perfectly
// linear, zero bank conflicts (was 7.37M conflict-cycles with row-major).
__global__ __launch_bounds__(256) void gemm_bt_part(const u16* __restrict__ A,
                                                    const u16* __restrict__ B,
                                                    u16* __restrict__ C0,
                                                    int N, int K, int ksplit) {
    __shared__ u16 lsA[2][128 * 32];   // 8 panels of 16 rows x 32 k (1024B each)
    __shared__ u16 lsB[2][128 * 32];
    const int tid  = threadIdx.x;
    const int lane = tid & 63;
    const int wv   = tid >> 6;          // wave 0..3
    const int wm   = wv >> 1, wn = wv & 1;
    const long m0 = (long)blockIdx.y * 128;
    const long n0 = (long)blockIdx.x * 128;
    const int kb = blockIdx.z * ksplit;
    const int ke = kb + ksplit;
    u16* C = C0 + (size_t)blockIdx.z * ((size_t)TTOK * N);

    f32x4 acc[4][4];
    #pragma unroll
    for (int i = 0; i < 4; ++i)
        #pragma unroll
        for (int j = 0; j < 4; ++j) acc[i][j] = f32x4{0.f, 0.f, 0.f, 0.f};

    const int sr = lane & 15;           // staging row within 16-row panel
    const int sc = lane >> 4;           // staging 8-elem k-chunk 0..3

    const u16* Abase = A + (m0 + wv * 32 + sr) * (long)K + sc * 8;
    const u16* Bbase = B + (n0 + wv * 32 + sr) * (long)K + sc * 8;
    const long rowK16 = 16 * (long)K;

    auto stage = [&](int k0, int buf) {
        glds16(Abase + k0,          &lsA[buf][(wv * 2    ) * 512]);
        glds16(Abase + k0 + rowK16, &lsA[buf][(wv * 2 + 1) * 512]);
        glds16(Bbase + k0,          &lsB[buf][(wv * 2    ) * 512]);
        glds16(Bbase + k0 + rowK16, &lsB[buf][(wv * 2 + 1) * 512]);
    };

    stage(kb, 0);
    int ib = 0;
    for (int k0 = kb; k0 < ke; k0 += 32, ib ^= 1) {
        __syncthreads();                 // drains stage(i); protects buf ib^1
        if (k0 + 32 < ke) stage(k0 + 32, ib ^ 1);
        bf16x8 af[4], bfg[4];
        #pragma unroll
        for (int mi = 0; mi < 4; ++mi)
            af[mi] = *(const bf16x8*)&lsA[ib][(wm * 4 + mi) * 512 + lane * 8];
        #pragma unroll
        for (int ni = 0; ni < 4; ++ni)
            bfg[ni] = *(const bf16x8*)&lsB[ib][(wn * 4 + ni) * 512 + lane * 8];
        #pragma unroll
        for (int mi = 0; mi < 4; ++mi)
            #pragma unroll
            for (int ni = 0; ni < 4; ++ni)
                acc[mi][ni] = __builtin_amdgcn_mfma_f32_16x16x32_bf16(af[mi], bfg[ni], acc[mi][ni], 0, 0, 0);
    }

    // epilogue: C/D layout col=lane&15, row=(lane>>4)*4+reg  [m89-verified]
    const int cr = (lane >> 4) * 4;
    const int cc = lane & 15;
    #pragma unroll
    for (int ni = 0; ni < 4; ++ni) {
        long col = n0 + wn * 64 + ni * 16 + cc;
        #pragma unroll
        for (int mi = 0; mi < 4; ++mi) {
            #pragma unroll
            for (int r2 = 0; r2 < 4; ++r2) {
                long row = m0 + wm * 64 + mi * 16 + cr + r2;
                C[row * (long)N + col] = f2bf(acc[mi][ni][r2]);
            }
        }
    }
}

// ---------------- RoPE (YaRN), consumes GEMM1 split-K partials + bias ----------------
__global__ __launch_bounds__(256) void rope_kernel(const u16* __restrict__ p1a,
                                                   const u16* __restrict__ p1b,
                                                   const float* __restrict__ b_qkv,
                                                   u16* __restrict__ qr,
                                                   u16* __restrict__ kr,
                                                   u16* __restrict__ vr) {
    const int t = blockIdx.x;
    const int tid = threadIdx.x;
    __shared__ float cs[32], sn[32];
    if (tid < 32) {
        float fi = (float)tid;
        float freq   = exp2f(17.1946032f * (fi * (1.0f / 32.0f)));   // 150000^(i/32)
        float interp = 1.0f / (32.0f * freq);
        float extra  = 1.0f / freq;
        float ramp   = (fi - 8.0927802f) * (1.0f / (17.3980220f - 8.0927802f));
        float rc     = fminf(fmaxf(ramp, 0.0f), 1.0f);               // = 1 - mask
        float invf   = interp * rc + extra * (1.0f - rc);
        float ang    = (float)t * invf;
        cs[tid] = cosf(ang) * 1.3465736f;                            // * concentration
        sn[tid] = sinf(ang) * 1.3465736f;
    }
    __syncthreads();
    const u16* rowA = p1a + (long)t * QKVD;
    const u16* rowB = p1b + (long)t * QKVD;
    auto pair = [&](int col) -> float2 {
        u32 ua = *(const u32*)(rowA + col);
        u32 ub = *(const u32*)(rowB + col);
        float2 bb = *(const float2*)(b_qkv + col);
        return make_float2(bflo(ua) + bflo(ub) + bb.x, bfhi(ua) + bfhi(ub) + bb.y);
    };
    // Q: 64 heads x 32 pairs
    for (int p = tid; p < 2048; p += 256) {
        int hd2 = p >> 5, i = p & 31;
        float2 ab = pair(hd2 * 64 + 2 * i);
        float o1 = ab.x * cs[i] - ab.y * sn[i];
        float o2 = ab.y * cs[i] + ab.x * sn[i];
        *(u32*)(qr + (long)t * QD + hd2 * 64 + 2 * i) = (u32)f2bf(o1) | ((u32)f2bf(o2) << 16);
    }
    // K: 8 heads x 32 pairs == 256 threads; head-major layout [kv][t][64]
    {
        int kv = tid >> 5, i = tid & 31;
        float2 ab = pair(QD + kv * 64 + 2 * i);
        float o1 = ab.x * cs[i] - ab.y * sn[i];
        float o2 = ab.y * cs[i] + ab.x * sn[i];
        *(u32*)(kr + ((long)kv * TTOK + t) * HD + 2 * i) = (u32)f2bf(o1) | ((u32)f2bf(o2) << 16);
    }
    // V: 8 heads x 64 = 256 u32; head-major [kv][t][64]
    {
        int kv = tid >> 5, d2 = tid & 31;
        float2 ab = pair(QD + 512 + kv * 64 + 2 * d2);
        *(u32*)(vr + ((long)kv * TTOK + t) * HD + 2 * d2) = (u32)f2bf(ab.x) | ((u32)f2bf(ab.y) << 16);
    }
}

// ---------------- MFMA sliding-window attention with sink ----------------
__global__ __launch_bounds__(256, 2) void attn_kernel(const u16* __restrict__ qr,
                                                      const u16* __restrict__ kr,
                                                      const u16* __restrict__ vr,
                                                      const float* __restrict__ sinks,
                                                      u16* __restrict__ o) {
    const int t0  = blockIdx.x * 16;
    const int h   = blockIdx.y;
    const int qhg = blockIdx.z;
    const int tid = threadIdx.x;
    const int lane = tid & 63, wv = tid >> 6;
    __shared__ __align__(16) u16 ks[144][72];    // K rows [key][64+pad]
    __shared__ __align__(16) u16 Vt[64][168];    // V^T [d][key], cols 144..159 zero
    __shared__ __align__(16) u16 P [4][16][168]; // per-wave P [token][key], cols 144..159 zero
    const u16* kb = kr + (long)h * TTOK * HD;
    const u16* vb = vr + (long)h * TTOK * HD;

    // stage K rows (coalesced)
    #pragma unroll
    for (int i = 0; i < 5; ++i) {
        int idx = i * 256 + tid;
        if (idx < 144 * 8) {
            int rr = idx >> 3, c = idx & 7;
            int tk = t0 - 128 + rr;
            int tks = tk < 0 ? 0 : tk;          // clamped; masked later
            *(uint4*)&ks[rr][c * 8] = *(const uint4*)(kb + (long)tks * HD + c * 8);
        }
    }
    // stage V transposed: thread -> one key, 8 dims per pass
    #pragma unroll
    for (int c4 = 0; c4 < 8; ++c4) {
        if (tid < 144) {
            int tk = t0 - 128 + tid;
            int tks = tk < 0 ? 0 : tk;
            uint4 v4 = *(const uint4*)(vb + (long)tks * HD + c4 * 8);
            int d0 = c4 * 8;
            Vt[d0+0][tid] = (u16)(v4.x & 0xffff); Vt[d0+1][tid] = (u16)(v4.x >> 16);
            Vt[d0+2][tid] = (u16)(v4.y & 0xffff); Vt[d0+3][tid] = (u16)(v4.y >> 16);
            Vt[d0+4][tid] = (u16)(v4.z & 0xffff); Vt[d0+5][tid] = (u16)(v4.z >> 16);
            Vt[d0+6][tid] = (u16)(v4.w & 0xffff); Vt[d0+7][tid] = (u16)(v4.w >> 16);
        }
    }
    if (tid < 128) {
        *(uint4*)&Vt[tid >> 1][144 + (tid & 1) * 8] = uint4{0, 0, 0, 0};
    }
    if (lane < 32) {
        *(uint4*)&P[wv][lane >> 1][144 + (lane & 1) * 8] = uint4{0, 0, 0, 0};
    }
    __syncthreads();

    const int qh   = qhg * 4 + wv;
    const int head = h * QMULT + qh;
    const int fr = lane & 15, fk = (lane >> 4) * 8;
    const int cr = (lane >> 4) * 4;

    const u16* qrow = qr + (long)(t0 + fr) * QD + head * HD;
    bf16x8 qf0 = *(const bf16x8*)(qrow + fk);
    bf16x8 qf1 = *(const bf16x8*)(qrow + 32 + fk);

    const int kmin = 128 - t0;          // kk >= kmin <=> key token >= 0
    float lsum[4] = {0.f, 0.f, 0.f, 0.f};

    for (int nt = 0; nt < 9; ++nt) {
        bf16x8 b0 = *(const bf16x8*)&ks[nt * 16 + fr][fk];
        bf16x8 b1 = *(const bf16x8*)&ks[nt * 16 + fr][32 + fk];
        f32x4 s = f32x4{0.f, 0.f, 0.f, 0.f};
        s = __builtin_amdgcn_mfma_f32_16x16x32_bf16(qf0, b0, s, 0, 0, 0);
        s = __builtin_amdgcn_mfma_f32_16x16x32_bf16(qf1, b1, s, 0, 0, 0);
        const int kk = nt * 16 + fr;    // C-layout col = lane&15
        #pragma unroll
        for (int r = 0; r < 4; ++r) {
            int row = cr + r;           // token index within tile
            bool valid = (kk >= row) && (kk <= row + 128) && (kk >= kmin);
            float p = valid ? __expf(s[r] * 0.125f) : 0.0f;
            lsum[r] += p;
            P[wv][row][kk] = f2bf(p);
        }
    }

    f32x4 oacc[4];
    #pragma unroll
    for (int dt = 0; dt < 4; ++dt) oacc[dt] = f32x4{0.f, 0.f, 0.f, 0.f};
    #pragma unroll
    for (int k5 = 0; k5 < 5; ++k5) {
        const int k0 = k5 * 32;
        bf16x8 pa = *(const bf16x8*)&P[wv][fr][k0 + fk];
        #pragma unroll
        for (int dt = 0; dt < 4; ++dt) {
            bf16x8 vf = *(const bf16x8*)&Vt[dt * 16 + fr][k0 + fk];
            oacc[dt] = __builtin_amdgcn_mfma_f32_16x16x32_bf16(pa, vf, oacc[dt], 0, 0, 0);
        }
    }

    #pragma unroll
    for (int r = 0; r < 4; ++r) {
        float v = lsum[r];
        v += __shfl_xor(v, 1);
        v += __shfl_xor(v, 2);
        v += __shfl_xor(v, 4);
        v += __shfl_xor(v, 8);
        lsum[r] = v;
    }
    const float sk = exp2f(sinks[head]);
    float inv[4];
    #pragma unroll
    for (int r = 0; r < 4; ++r) inv[r] = 1.0f / (lsum[r] + sk);

    #pragma unroll
    for (int dt = 0; dt < 4; ++dt) {
        #pragma unroll
        for (int r = 0; r < 4; ++r) {
            o[(long)(t0 + cr + r) * QD + head * HD + dt * 16 + fr] = f2bf(oacc[dt][r] * inv[r]);
        }
    }
}

// ---------------- reduce GEMM2 partials + bias + residual -> out ----------------
__global__ __launch_bounds__(256) void reduce2_kernel(const u16* __restrict__ p2a,
                                                      const u16* __restrict__ p2b,
                                                      const float* __restrict__ x,
                                                      const float* __restrict__ b_out,
                                                      float* __restrict__ out) {
    const int row = blockIdx.y;
    const int c4 = blockIdx.x * 256 + threadIdx.x;   // float4 index within row
    if (c4 >= 720) return;
    const int col = c4 * 4;
    ushort4 ua = *(const ushort4*)(p2a + (long)row * NPAD + col);
    ushort4 ub = *(const ushort4*)(p2b + (long)row * NPAD + col);
    float4 xv = *(const float4*)(x + (long)row * HIDDEN + col);
    float4 bv = *(const float4*)(b_out + col);
    float4 o;
    o.x = xv.x + bv.x + __uint_as_float((u32)ua.x << 16) + __uint_as_float((u32)ub.x << 16);
    o.y = xv.y + bv.y + __uint_as_float((u32)ua.y << 16) + __uint_as_float((u32)ub.y << 16);
    o.z = xv.z + bv.z + __uint_as_float((u32)ua.z << 16) + __uint_as_float((u32)ub.z << 16);
    o.w = xv.w + bv.w + __uint_as_float((u32)ua.w << 16) + __uint_as_float((u32)ub.w << 16);
    *(float4*)(out + (long)row * HIDDEN + col) = o;
}

// ---------------- launcher ----------------
extern "C" void kernel_launch(void* const* d_in, const int* in_sizes, int n_in,
                              void* d_out, int out_size, void* d_ws, size_t ws_size,
                              hipStream_t stream) {
    const float* x      = (const float*)d_in[0];
    const float* nscale = (const float*)d_in[1];
    const float* w_qkv  = (const float*)d_in[2];
    const float* b_qkv  = (const float*)d_in[3];
    const float* sinks  = (const float*)d_in[4];
    const float* w_out  = (const float*)d_in[5];
    const float* b_out  = (const float*)d_in[6];
    float* out = (float*)d_out;

    char* ws = (char*)d_ws;
    size_t off = 0;
    auto alloc = [&](size_t bytes) { void* p = ws + off; off += (bytes + 255) & ~(size_t)255; return p; };
    u16* wqkv_bf = (u16*)alloc((size_t)QKVD * HIDDEN * 2);     // 29.5 MB
    u16* wout_bf = (u16*)alloc((size_t)NPAD * QD * 2);         // 24.1 MB
    u16* h       = (u16*)alloc((size_t)TTOK * HIDDEN * 2);     // 11.8 MB
    u16* p1      = (u16*)alloc((size_t)2 * TTOK * QKVD * 2);   // 42.0 MB (2 splits)
    u16* qrot    = (u16*)alloc((size_t)TTOK * QD * 2);         // 16.8 MB
    u16* krot    = (u16*)alloc((size_t)NKV * TTOK * HD * 2);   // 2.1 MB
    u16* vrot    = (u16*)alloc((size_t)NKV * TTOK * HD * 2);   // 2.1 MB
    // aliases (dead-after analysis):
    u16* attn = wqkv_bf;               // wqkv_bf dead after gemm1; attn [2048][4096] = 16.8 MB
    u16* p2   = p1;                    // p1 dead after rope; p2 = 2 x [2048][2944] = 24.1 MB

    prep_kernel<<<PREP_QKV_BLOCKS + PREP_WOUT_BLOCKS + PREP_RMS_BLOCKS, 256, 0, stream>>>(
        w_qkv, wqkv_bf, w_out, wout_bf, x, nscale, h);
    gemm_bt_part<<<dim3(QKVD / 128, TTOK / 128, 2), 256, 0, stream>>>(
        h, wqkv_bf, p1, QKVD, HIDDEN, HIDDEN / 2);
    rope_kernel<<<TTOK, 256, 0, stream>>>(
        p1, p1 + (size_t)TTOK * QKVD, b_qkv, qrot, krot, vrot);
    attn_kernel<<<dim3(TTOK / 16, NKV, 2), 256, 0, stream>>>(qrot, krot, vrot, sinks, attn);
    gemm_bt_part<<<dim3(NPAD / 128, TTOK / 128, 2), 256, 0, stream>>>(
        attn, wout_bf, p2, NPAD, QD, QD / 2);
    reduce2_kernel<<<dim3(3, TTOK), 256, 0, stream>>>(
        p2, p2 + (size_t)TTOK * NPAD, x, b_out, out);
}